// Round 1
// baseline (426.637 us; speedup 1.0000x reference)
//
#include <hip/hip_runtime.h>

// out[t, d] = x[t, d] * gain[d]
// gain[d] = sum_n cos(n * OMEGA * DT - eps[n,d] * DT)
// eps[n,d] = floquet_energies[n,d] * (1 + 0.1 * drive_weights[n])
// coupling_matrix unused.

#define F_DT 0.01f
#define F_OMEGA 1.0f

__global__ void gain_kernel(const float* __restrict__ fe,
                            const float* __restrict__ dw,
                            float* __restrict__ gain, int M, int D) {
    int d = blockIdx.x * blockDim.x + threadIdx.x;
    if (d >= D) return;
    float g = 0.0f;
    for (int n = 0; n < M; ++n) {
        float eps = fe[(long long)n * D + d] * (1.0f + 0.1f * dw[n]);
        g += cosf((float)n * (F_OMEGA * F_DT) - eps * F_DT);
    }
    gain[d] = g;
}

__global__ void scale_kernel(const float4* __restrict__ x,
                             const float4* __restrict__ gain4,
                             float4* __restrict__ out,
                             long long n4, int Dq) {
    long long i = (long long)blockIdx.x * blockDim.x + threadIdx.x;
    if (i >= n4) return;
    // Dq = D/4; D=4096 -> Dq=1024 (power of two)
    long long di = ((Dq & (Dq - 1)) == 0) ? (i & (long long)(Dq - 1)) : (i % Dq);
    float4 xv = x[i];
    float4 gv = gain4[di];
    float4 o;
    o.x = xv.x * gv.x;
    o.y = xv.y * gv.y;
    o.z = xv.z * gv.z;
    o.w = xv.w * gv.w;
    out[i] = o;
}

extern "C" void kernel_launch(void* const* d_in, const int* in_sizes, int n_in,
                              void* d_out, int out_size, void* d_ws, size_t ws_size,
                              hipStream_t stream) {
    const float* x  = (const float*)d_in[0];
    const float* fe = (const float*)d_in[1];
    const float* dw = (const float*)d_in[2];
    // d_in[3] = coupling_matrix, unused by the forward

    float* out  = (float*)d_out;
    float* gain = (float*)d_ws;   // D floats of scratch

    int M = in_sizes[2];                 // drive_weights: [M]
    int D = in_sizes[1] / M;             // floquet_energies: [M, D]
    long long n = (long long)in_sizes[0];

    // 1) gain[d], one thread per d
    {
        int threads = 256;
        int blocks = (D + threads - 1) / threads;
        gain_kernel<<<blocks, threads, 0, stream>>>(fe, dw, gain, M, D);
    }

    // 2) elementwise scale, float4-vectorized (D % 4 == 0, n % 4 == 0)
    {
        long long n4 = n / 4;
        int Dq = D / 4;
        int threads = 256;
        long long blocks = (n4 + threads - 1) / threads;
        scale_kernel<<<(int)blocks, threads, 0, stream>>>(
            (const float4*)x, (const float4*)gain, (float4*)out, n4, Dq);
    }
}